// Round 1
// baseline (110.337 us; speedup 1.0000x reference)
//
#include <hip/hip_runtime.h>
#include <math.h>

#define DIM    512
#define REDUC  64
#define T_FULL 4096
#define NB     32
#define N_SAMP 408     // ceil(4076/10)
#define N_LOC  20
#define N_ROWS 428     // per batch: 408 sampled + 20 local
#define EPS    1e-5f

// monotone encoding for float atomic max (order-independent, deterministic)
__device__ __forceinline__ unsigned enc_f(float x) {
    unsigned u = __float_as_uint(x);
    return (u & 0x80000000u) ? ~u : (u | 0x80000000u);
}
__device__ __forceinline__ float dec_f(unsigned e) {
    unsigned u = (e & 0x80000000u) ? (e & 0x7FFFFFFFu) : ~e;
    return __uint_as_float(u);
}

// Stage 1: comp = LN(relu(x @ W1 + b1)) for the 428 needed rows per batch.
// One wave handles 4 rows; lane j owns output dim j (0..63).
// Sampled rows -> atomicMax into encoded past_pooled; local rows -> ws.
__global__ __launch_bounds__(256) void k1_rows(
        const float* __restrict__ obs,
        const float* __restrict__ W1, const float* __restrict__ b1,
        const float* __restrict__ g1, const float* __restrict__ beta1,
        unsigned* __restrict__ pp_enc, float* __restrict__ present)
{
    const int lane = threadIdx.x & 63;
    const int wave = threadIdx.x >> 6;
    const int base = (blockIdx.x * 4 + wave) * 4;   // first of 4 row-tasks

    const float4* xp[4];
    int bidx[4], ridx[4];
    float acc[4];
#pragma unroll
    for (int r = 0; r < 4; ++r) {
        int idx = base + r;                 // < 32*428 = 13696
        int b   = idx / N_ROWS;
        int rr  = idx - b * N_ROWS;
        int t   = (rr < N_SAMP) ? rr * 10 : (T_FULL - N_LOC) + (rr - N_SAMP);
        bidx[r] = b; ridx[r] = rr;
        xp[r] = (const float4*)(obs + ((size_t)b * T_FULL + t) * DIM);
        acc[r] = 0.f;
    }

    const float* w1l = W1 + lane;           // W1[k][lane] = W1[k*64 + lane]
    for (int k4 = 0; k4 < DIM / 4; ++k4) {
        float4 x0 = xp[0][k4];
        float4 x1 = xp[1][k4];
        float4 x2 = xp[2][k4];
        float4 x3 = xp[3][k4];
        float w;
        w = w1l[(k4 * 4 + 0) * REDUC];
        acc[0] = fmaf(x0.x, w, acc[0]); acc[1] = fmaf(x1.x, w, acc[1]);
        acc[2] = fmaf(x2.x, w, acc[2]); acc[3] = fmaf(x3.x, w, acc[3]);
        w = w1l[(k4 * 4 + 1) * REDUC];
        acc[0] = fmaf(x0.y, w, acc[0]); acc[1] = fmaf(x1.y, w, acc[1]);
        acc[2] = fmaf(x2.y, w, acc[2]); acc[3] = fmaf(x3.y, w, acc[3]);
        w = w1l[(k4 * 4 + 2) * REDUC];
        acc[0] = fmaf(x0.z, w, acc[0]); acc[1] = fmaf(x1.z, w, acc[1]);
        acc[2] = fmaf(x2.z, w, acc[2]); acc[3] = fmaf(x3.z, w, acc[3]);
        w = w1l[(k4 * 4 + 3) * REDUC];
        acc[0] = fmaf(x0.w, w, acc[0]); acc[1] = fmaf(x1.w, w, acc[1]);
        acc[2] = fmaf(x2.w, w, acc[2]); acc[3] = fmaf(x3.w, w, acc[3]);
    }

    const float g1v = g1[lane], be1v = beta1[lane], b1v = b1[lane];
#pragma unroll
    for (int r = 0; r < 4; ++r) {
        float y = fmaxf(acc[r] + b1v, 0.f);
        // LN over the 64 lanes of this wave
        float s = y;
#pragma unroll
        for (int off = 32; off >= 1; off >>= 1) s += __shfl_xor(s, off);
        float mu = s * (1.f / 64.f);
        float d  = y - mu;
        float v  = d * d;
#pragma unroll
        for (int off = 32; off >= 1; off >>= 1) v += __shfl_xor(v, off);
        float c = d * rsqrtf(v * (1.f / 64.f) + EPS) * g1v + be1v;

        if (ridx[r] < N_SAMP) {
            atomicMax(&pp_enc[bidx[r] * REDUC + lane], enc_f(c));
        } else {
            present[(bidx[r] * N_LOC + (ridx[r] - N_SAMP)) * REDUC + lane] = c;
        }
    }
}

// Stage 2: per (batch, local-step): g = max(past_pooled, cummax(present[0..t]));
// out = LN(relu(g @ W2 + b2)). Block = 512 threads, one per output dim.
__global__ __launch_bounds__(512) void k2_out(
        const unsigned* __restrict__ pp_enc,
        const float* __restrict__ present,
        const float* __restrict__ W2, const float* __restrict__ b2,
        const float* __restrict__ g2, const float* __restrict__ beta2,
        float* __restrict__ out)
{
    __shared__ float gsh[REDUC];
    __shared__ float red[16];

    const int b   = blockIdx.x / N_LOC;
    const int t   = blockIdx.x % N_LOC;
    const int tid = threadIdx.x;

    if (tid < REDUC) {
        float m = dec_f(pp_enc[b * REDUC + tid]);
        for (int r = 0; r <= t; ++r)
            m = fmaxf(m, present[(b * N_LOC + r) * REDUC + tid]);
        gsh[tid] = m;
    }
    __syncthreads();

    float acc = b2[tid];
#pragma unroll 8
    for (int k = 0; k < REDUC; ++k)
        acc = fmaf(gsh[k], W2[k * DIM + tid], acc);
    float y = fmaxf(acc, 0.f);

    const int lane = tid & 63, wv = tid >> 6;
    // block LN over 512: wave shuffle-reduce, then LDS across 8 waves
    float s = y;
#pragma unroll
    for (int off = 32; off >= 1; off >>= 1) s += __shfl_xor(s, off);
    if (lane == 0) red[wv] = s;
    __syncthreads();
    float tot = red[0] + red[1] + red[2] + red[3] +
                red[4] + red[5] + red[6] + red[7];
    float mu = tot * (1.f / 512.f);
    float d  = y - mu;

    float v = d * d;
#pragma unroll
    for (int off = 32; off >= 1; off >>= 1) v += __shfl_xor(v, off);
    if (lane == 0) red[8 + wv] = v;
    __syncthreads();
    float vtot = red[8] + red[9] + red[10] + red[11] +
                 red[12] + red[13] + red[14] + red[15];
    float var = vtot * (1.f / 512.f);

    out[((size_t)b * N_LOC + t) * DIM + tid] =
        d * rsqrtf(var + EPS) * g2[tid] + beta2[tid];
}

extern "C" void kernel_launch(void* const* d_in, const int* in_sizes, int n_in,
                              void* d_out, int out_size, void* d_ws, size_t ws_size,
                              hipStream_t stream) {
    const float* obs   = (const float*)d_in[0];
    const float* W1    = (const float*)d_in[1];
    const float* b1    = (const float*)d_in[2];
    const float* g1    = (const float*)d_in[3];
    const float* beta1 = (const float*)d_in[4];
    const float* W2    = (const float*)d_in[5];
    const float* b2    = (const float*)d_in[6];
    const float* g2    = (const float*)d_in[7];
    const float* beta2 = (const float*)d_in[8];
    float* out = (float*)d_out;

    unsigned* pp_enc = (unsigned*)d_ws;                          // 32*64 u32 = 8 KB
    float* present   = (float*)((char*)d_ws + NB * REDUC * 4);   // 32*20*64 f32 = 160 KB

    // re-init encoded past_pooled every call (enc==0 < enc(any finite float))
    hipMemsetAsync(d_ws, 0, NB * REDUC * sizeof(unsigned), stream);

    // 32*428 = 13696 row-tasks; 16 rows/block (4 waves x 4 rows) -> 856 blocks
    k1_rows<<<856, 256, 0, stream>>>(obs, W1, b1, g1, beta1, pp_enc, present);
    // 32 batches x 20 local steps
    k2_out<<<NB * N_LOC, 512, 0, stream>>>(pp_enc, present, W2, b2, g2, beta2, out);
}

// Round 2
// 79.082 us; speedup vs baseline: 1.3952x; 1.3952x over previous
//
#include <hip/hip_runtime.h>
#include <math.h>

#define DIM    512
#define REDUC  64
#define T_FULL 4096
#define NB     32
#define SR     10
#define N_SAMP 408     // ceil(4076/10): t = 0,10,...,4070
#define N_LOC  20
#define N_ROWS 428     // per batch: 408 sampled + 20 local
#define EPS    1e-5f

#define ROWS_PER_WAVE   8
#define WAVES_PER_BLOCK 4
#define ROWS_PER_BLOCK  32   // 4 waves x 8 rows
#define BLOCKS_PER_BATCH 14  // ceil(428/32); block 13 has 12 (local-only) rows
#define NPART 13             // blocks 0..12 contain sampled rows

// Stage 1: comp = LN(relu(x @ W1 + b1)) for the 428 needed rows per batch.
// Wave handles 8 consecutive rows; lane j owns output dim j.
// x loads are wave-uniform (readfirstlane'd wave id) -> scalar s_load path.
// Sampled rows fold into a per-block partial max (deterministic, no atomics).
__global__ __launch_bounds__(256) void k1_rows(
        const float* __restrict__ obs,
        const float* __restrict__ W1, const float* __restrict__ b1,
        const float* __restrict__ g1, const float* __restrict__ beta1,
        float* __restrict__ partials, float* __restrict__ present)
{
    const int lane = threadIdx.x & 63;
    const int wv   = __builtin_amdgcn_readfirstlane((int)(threadIdx.x >> 6));
    const int b    = blockIdx.y;
    const int blk  = blockIdx.x;
    const int row0 = blk * ROWS_PER_BLOCK + wv * ROWS_PER_WAVE;

    const float4* xp[ROWS_PER_WAVE];
    float acc[ROWS_PER_WAVE];
#pragma unroll
    for (int r = 0; r < ROWS_PER_WAVE; ++r) {
        int rr = row0 + r;
        int rc = (rr < N_ROWS) ? rr : 0;   // clamp invalid rows to a safe addr
        int t  = (rc < N_SAMP) ? rc * SR : (T_FULL - N_LOC) + (rc - N_SAMP);
        xp[r]  = (const float4*)(obs + ((size_t)b * T_FULL + t) * DIM);
        acc[r] = 0.f;
    }

    const float* w1l = W1 + lane;          // W1[k][lane] = W1[k*64 + lane]
    for (int k4 = 0; k4 < DIM / 4; ++k4) {
        float wa = w1l[(k4 * 4 + 0) * REDUC];
        float wb = w1l[(k4 * 4 + 1) * REDUC];
        float wc = w1l[(k4 * 4 + 2) * REDUC];
        float wd = w1l[(k4 * 4 + 3) * REDUC];
#pragma unroll
        for (int r = 0; r < ROWS_PER_WAVE; ++r) {
            float4 x = xp[r][k4];          // wave-uniform -> s_load_dwordx4
            acc[r] = fmaf(x.x, wa, acc[r]);
            acc[r] = fmaf(x.y, wb, acc[r]);
            acc[r] = fmaf(x.z, wc, acc[r]);
            acc[r] = fmaf(x.w, wd, acc[r]);
        }
    }

    const float g1v = g1[lane], be1v = beta1[lane], b1v = b1[lane];
    float wmax = -INFINITY;
#pragma unroll
    for (int r = 0; r < ROWS_PER_WAVE; ++r) {
        int rr = row0 + r;
        float y = fmaxf(acc[r] + b1v, 0.f);
        float s = y;
#pragma unroll
        for (int off = 32; off >= 1; off >>= 1) s += __shfl_xor(s, off);
        float mu = s * (1.f / 64.f);
        float d  = y - mu;
        float v  = d * d;
#pragma unroll
        for (int off = 32; off >= 1; off >>= 1) v += __shfl_xor(v, off);
        float c = d * rsqrtf(v * (1.f / 64.f) + EPS) * g1v + be1v;

        if (rr < N_SAMP) {
            wmax = fmaxf(wmax, c);
        } else if (rr < N_ROWS) {
            present[((size_t)b * N_LOC + (rr - N_SAMP)) * REDUC + lane] = c;
        }
    }

    __shared__ float pmax[WAVES_PER_BLOCK][REDUC];
    pmax[wv][lane] = wmax;
    __syncthreads();
    if (wv == 0 && blk < NPART) {
        float m = fmaxf(fmaxf(pmax[0][lane], pmax[1][lane]),
                        fmaxf(pmax[2][lane], pmax[3][lane]));
        partials[((size_t)b * NPART + blk) * REDUC + lane] = m;
    }
}

// Stage 2: per (batch, local-step): g = max(partials 0..12, cummax(present[0..t]));
// out = LN(relu(g @ W2 + b2)). Block = 512 threads, one per output dim.
__global__ __launch_bounds__(512) void k2_out(
        const float* __restrict__ partials,
        const float* __restrict__ present,
        const float* __restrict__ W2, const float* __restrict__ b2,
        const float* __restrict__ g2, const float* __restrict__ beta2,
        float* __restrict__ out)
{
    __shared__ float gsh[REDUC];
    __shared__ float red[16];

    const int b   = blockIdx.x / N_LOC;
    const int t   = blockIdx.x % N_LOC;
    const int tid = threadIdx.x;

    if (tid < REDUC) {
        float m = -INFINITY;
#pragma unroll
        for (int p = 0; p < NPART; ++p)
            m = fmaxf(m, partials[((size_t)b * NPART + p) * REDUC + tid]);
        for (int r = 0; r <= t; ++r)
            m = fmaxf(m, present[((size_t)b * N_LOC + r) * REDUC + tid]);
        gsh[tid] = m;
    }
    __syncthreads();

    float acc = b2[tid];
#pragma unroll 8
    for (int k = 0; k < REDUC; ++k)
        acc = fmaf(gsh[k], W2[k * DIM + tid], acc);
    float y = fmaxf(acc, 0.f);

    const int lane = tid & 63, wv = tid >> 6;
    float s = y;
#pragma unroll
    for (int off = 32; off >= 1; off >>= 1) s += __shfl_xor(s, off);
    if (lane == 0) red[wv] = s;
    __syncthreads();
    float tot = red[0] + red[1] + red[2] + red[3] +
                red[4] + red[5] + red[6] + red[7];
    float mu = tot * (1.f / 512.f);
    float d  = y - mu;

    float v = d * d;
#pragma unroll
    for (int off = 32; off >= 1; off >>= 1) v += __shfl_xor(v, off);
    if (lane == 0) red[8 + wv] = v;
    __syncthreads();
    float vtot = red[8] + red[9] + red[10] + red[11] +
                 red[12] + red[13] + red[14] + red[15];
    float var = vtot * (1.f / 512.f);

    out[((size_t)b * N_LOC + t) * DIM + tid] =
        d * rsqrtf(var + EPS) * g2[tid] + beta2[tid];
}

extern "C" void kernel_launch(void* const* d_in, const int* in_sizes, int n_in,
                              void* d_out, int out_size, void* d_ws, size_t ws_size,
                              hipStream_t stream) {
    const float* obs   = (const float*)d_in[0];
    const float* W1    = (const float*)d_in[1];
    const float* b1    = (const float*)d_in[2];
    const float* g1    = (const float*)d_in[3];
    const float* beta1 = (const float*)d_in[4];
    const float* W2    = (const float*)d_in[5];
    const float* b2    = (const float*)d_in[6];
    const float* g2    = (const float*)d_in[7];
    const float* beta2 = (const float*)d_in[8];
    float* out = (float*)d_out;

    // ws layout: partials [32][13][64] f32 (106496 B), then present [32][20][64] f32
    float* partials = (float*)d_ws;
    float* present  = (float*)((char*)d_ws + (size_t)NB * NPART * REDUC * 4);

    dim3 g1d(BLOCKS_PER_BATCH, NB);
    k1_rows<<<g1d, WAVES_PER_BLOCK * 64, 0, stream>>>(
        obs, W1, b1, g1, beta1, partials, present);
    k2_out<<<NB * N_LOC, 512, 0, stream>>>(
        partials, present, W2, b2, g2, beta2, out);
}

// Round 3
// 69.766 us; speedup vs baseline: 1.5815x; 1.1335x over previous
//
#include <hip/hip_runtime.h>
#include <math.h>

#define DIM    512
#define REDUC  64
#define T_FULL 4096
#define NB     32
#define SR     10
#define N_SAMP 408     // t = 0,10,...,4070
#define N_LOC  20
#define N_ROWS 428     // per batch: 408 sampled + 20 local
#define EPS    1e-5f

#define RPW   8        // rows per wave
#define WPB   4        // waves per block
#define RPB   32       // rows per block
#define BPB   14       // blocks per batch (block 13: 12 local-only rows)
#define NPART 13       // blocks containing sampled rows
#define KC    128      // K chunk staged in LDS
#define NCH   4        // 512 / 128

#define GLDS(g, l) __builtin_amdgcn_global_load_lds( \
    (const __attribute__((address_space(1))) void*)(g), \
    (__attribute__((address_space(3))) void*)(l), 16, 0, 0)

// Stage 1: comp = LN(relu(x @ W1 + b1)) for the 428 needed rows per batch.
// Wave owns 8 rows, lane owns output dim j. x staged global->LDS in K-chunks
// (double-buffered, coalesced global_load_lds); x consumed as uniform
// broadcast ds_read_b128; W1 from L1/L2 (block's 4 waves reuse each chunk).
__global__ __launch_bounds__(256) void k1_rows(
        const float* __restrict__ obs,
        const float* __restrict__ W1, const float* __restrict__ b1,
        const float* __restrict__ g1, const float* __restrict__ beta1,
        float* __restrict__ partials, float* __restrict__ present)
{
    __shared__ float ldsx[2][RPB][KC];     // 32 KB
    __shared__ float pmax[WPB][REDUC];

    const int lane = threadIdx.x & 63;
    const int wv   = __builtin_amdgcn_readfirstlane((int)(threadIdx.x >> 6));
    const int b    = blockIdx.y;
    const int blk  = blockIdx.x;
    const int row0 = blk * RPB + wv * RPW;

    // per-row global base pointers (invalid rows clamped to row 0, discarded)
    const float* xr[RPW];
#pragma unroll
    for (int r = 0; r < RPW; ++r) {
        int rr = row0 + r;
        int rc = (rr < N_ROWS) ? rr : 0;
        int t  = (rc < N_SAMP) ? rc * SR : (T_FULL - N_LOC) + (rc - N_SAMP);
        xr[r]  = obs + ((size_t)b * T_FULL + t) * DIM;
    }

    const int lsub = (lane & 31) * 4;   // float offset inside 128-float chunk
    const int hi   = lane >> 5;         // which row of the staged pair

    // prologue: stage chunk 0 into buf 0 (call i covers rows 2i, 2i+1)
#pragma unroll
    for (int i = 0; i < 4; ++i) {
        const float* gp = (hi ? xr[2*i+1] : xr[2*i]) + lsub;
        GLDS(gp, &ldsx[0][wv*RPW + 2*i][0]);
    }

    float acc[RPW];
#pragma unroll
    for (int r = 0; r < RPW; ++r) acc[r] = 0.f;

    __syncthreads();

    int buf = 0;
    for (int c = 0; c < NCH; ++c) {
        if (c + 1 < NCH) {              // prefetch next chunk into other buf
            const int coff = (c + 1) * KC + lsub;
#pragma unroll
            for (int i = 0; i < 4; ++i) {
                const float* gp = (hi ? xr[2*i+1] : xr[2*i]) + coff;
                GLDS(gp, &ldsx[buf ^ 1][wv*RPW + 2*i][0]);
            }
        }
        const float* w1p = W1 + (size_t)(c * KC) * REDUC + lane;
#pragma unroll 8
        for (int kk = 0; kk < KC / 4; ++kk) {
            float wa = w1p[(kk*4 + 0) * REDUC];
            float wb = w1p[(kk*4 + 1) * REDUC];
            float wc = w1p[(kk*4 + 2) * REDUC];
            float wd = w1p[(kk*4 + 3) * REDUC];
#pragma unroll
            for (int r = 0; r < RPW; ++r) {
                float4 x = *(const float4*)&ldsx[buf][wv*RPW + r][kk*4];
                acc[r] = fmaf(x.x, wa, acc[r]);
                acc[r] = fmaf(x.y, wb, acc[r]);
                acc[r] = fmaf(x.z, wc, acc[r]);
                acc[r] = fmaf(x.w, wd, acc[r]);
            }
        }
        __syncthreads();                // also drains prefetch vmcnt
        buf ^= 1;
    }

    const float g1v = g1[lane], be1v = beta1[lane], b1v = b1[lane];
    float wmax = -INFINITY;
#pragma unroll
    for (int r = 0; r < RPW; ++r) {
        int rr = row0 + r;
        float y = fmaxf(acc[r] + b1v, 0.f);
        float s = y;
#pragma unroll
        for (int off = 32; off >= 1; off >>= 1) s += __shfl_xor(s, off);
        float mu = s * (1.f / 64.f);
        float d  = y - mu;
        float v  = d * d;
#pragma unroll
        for (int off = 32; off >= 1; off >>= 1) v += __shfl_xor(v, off);
        float cres = d * rsqrtf(v * (1.f / 64.f) + EPS) * g1v + be1v;

        if (rr < N_SAMP) {
            wmax = fmaxf(wmax, cres);
        } else if (rr < N_ROWS) {
            present[((size_t)b * N_LOC + (rr - N_SAMP)) * REDUC + lane] = cres;
        }
    }

    pmax[wv][lane] = wmax;
    __syncthreads();
    if (wv == 0 && blk < NPART) {
        float m = fmaxf(fmaxf(pmax[0][lane], pmax[1][lane]),
                        fmaxf(pmax[2][lane], pmax[3][lane]));
        partials[((size_t)b * NPART + blk) * REDUC + lane] = m;
    }
}

// Stage 2: per (batch, local-step): g = max(partials, cummax(present[0..t]));
// out = LN(relu(g @ W2 + b2)). 512 threads; max phase parallel over 8 slices.
__global__ __launch_bounds__(512) void k2_out(
        const float* __restrict__ partials,
        const float* __restrict__ present,
        const float* __restrict__ W2, const float* __restrict__ b2,
        const float* __restrict__ g2, const float* __restrict__ beta2,
        float* __restrict__ out)
{
    __shared__ float msh[8][REDUC];
    __shared__ float gsh[REDUC];
    __shared__ float red[16];

    const int b   = blockIdx.x / N_LOC;
    const int t   = blockIdx.x % N_LOC;
    const int tid = threadIdx.x;
    const int j   = tid & 63;
    const int s8  = tid >> 6;           // slice 0..7

    float m = -INFINITY;
    for (int p = s8; p < NPART; p += 8)
        m = fmaxf(m, partials[((size_t)b * NPART + p) * REDUC + j]);
    for (int r = s8; r <= t; r += 8)
        m = fmaxf(m, present[((size_t)b * N_LOC + r) * REDUC + j]);
    msh[s8][j] = m;
    __syncthreads();
    if (tid < REDUC) {
        float mm = msh[0][tid];
#pragma unroll
        for (int ss = 1; ss < 8; ++ss) mm = fmaxf(mm, msh[ss][tid]);
        gsh[tid] = mm;
    }
    __syncthreads();

    float acc = b2[tid];
#pragma unroll 8
    for (int k = 0; k < REDUC; ++k)
        acc = fmaf(gsh[k], W2[k * DIM + tid], acc);
    float y = fmaxf(acc, 0.f);

    const int lane = tid & 63, wv = tid >> 6;
    float s = y;
#pragma unroll
    for (int off = 32; off >= 1; off >>= 1) s += __shfl_xor(s, off);
    if (lane == 0) red[wv] = s;
    __syncthreads();
    float tot = red[0] + red[1] + red[2] + red[3] +
                red[4] + red[5] + red[6] + red[7];
    float mu = tot * (1.f / 512.f);
    float d  = y - mu;

    float v = d * d;
#pragma unroll
    for (int off = 32; off >= 1; off >>= 1) v += __shfl_xor(v, off);
    if (lane == 0) red[8 + wv] = v;
    __syncthreads();
    float vtot = red[8] + red[9] + red[10] + red[11] +
                 red[12] + red[13] + red[14] + red[15];
    float var = vtot * (1.f / 512.f);

    out[((size_t)b * N_LOC + t) * DIM + tid] =
        d * rsqrtf(var + EPS) * g2[tid] + beta2[tid];
}

extern "C" void kernel_launch(void* const* d_in, const int* in_sizes, int n_in,
                              void* d_out, int out_size, void* d_ws, size_t ws_size,
                              hipStream_t stream) {
    const float* obs   = (const float*)d_in[0];
    const float* W1    = (const float*)d_in[1];
    const float* b1    = (const float*)d_in[2];
    const float* g1    = (const float*)d_in[3];
    const float* beta1 = (const float*)d_in[4];
    const float* W2    = (const float*)d_in[5];
    const float* b2    = (const float*)d_in[6];
    const float* g2    = (const float*)d_in[7];
    const float* beta2 = (const float*)d_in[8];
    float* out = (float*)d_out;

    // ws: partials [32][13][64] f32, then present [32][20][64] f32
    float* partials = (float*)d_ws;
    float* present  = (float*)((char*)d_ws + (size_t)NB * NPART * REDUC * 4);

    dim3 g1d(BPB, NB);
    k1_rows<<<g1d, WPB * 64, 0, stream>>>(
        obs, W1, b1, g1, beta1, partials, present);
    k2_out<<<NB * N_LOC, 512, 0, stream>>>(
        partials, present, W2, b2, g2, beta2, out);
}

// Round 4
// 28.628 us; speedup vs baseline: 3.8542x; 2.4370x over previous
//
#include <hip/hip_runtime.h>
#include <math.h>

#define DIM    512
#define REDUC  64
#define T_FULL 4096
#define NB     32
#define SR     10
#define N_SAMP 408     // t = 0,10,...,4070
#define N_LOC  20
#define N_ROWS 428     // per batch: 408 sampled + 20 local
#define EPS    1e-5f

#define RPB   32       // rows per block (2 M-tiles of 16)
#define BPB   14       // blocks per batch (block 13: 12 local-only rows)
#define NPART 13       // blocks containing sampled rows

typedef short bf16x8 __attribute__((ext_vector_type(8)));   // 8 bf16 in 4 VGPRs
typedef float f32x4  __attribute__((ext_vector_type(4)));

union Frag { bf16x8 v; uint4 u; };

__device__ __forceinline__ unsigned bf16_rne(float f) {     // round-nearest-even
    unsigned u = __float_as_uint(f);
    return (u + 0x7fffu + ((u >> 16) & 1u)) >> 16;
}
__device__ __forceinline__ unsigned pack2(float lo, float hi) {
    return bf16_rne(lo) | (bf16_rne(hi) << 16);
}

// k0: pre-pack W1 (f32 [512][64]) into bf16 B-fragment order:
// w1p[sg][tile][lane] (16B): lane l holds W1[32*sg + 8*(l>>4) + f][16*tile + (l&15)]
__global__ __launch_bounds__(256) void k0_pack(const float* __restrict__ W1,
                                               uint4* __restrict__ w1p) {
    const int sg = blockIdx.x;                 // K-step 0..15
    const int t  = threadIdx.x;
    const int tile = t >> 6, l = t & 63;
    const int k0 = 32 * sg + 8 * (l >> 4);
    const int j  = 16 * tile + (l & 15);
    float v[8];
#pragma unroll
    for (int f = 0; f < 8; ++f) v[f] = W1[(size_t)(k0 + f) * REDUC + j];
    uint4 o;
    o.x = pack2(v[0], v[1]); o.y = pack2(v[2], v[3]);
    o.z = pack2(v[4], v[5]); o.w = pack2(v[6], v[7]);
    w1p[sg * 256 + t] = o;
}

// k1: comp = LN(relu(x @ W1 + b1)) for the 428 needed rows per batch, via
// bf16 MFMA 16x16x32. Block = 4 waves = 32 rows x 64 j. Wave w: M-tile w>>1,
// N-half w&1 (2 accumulator tiles). x reg-staged f32->bf16 into LDS A-frags
// (double-buffered, K-chunk 64); W1 read as packed B-frags from L1/L2.
__global__ __launch_bounds__(256) void k1_rows(
        const float* __restrict__ obs, const uint4* __restrict__ w1p,
        const float* __restrict__ b1, const float* __restrict__ g1,
        const float* __restrict__ beta1,
        float* __restrict__ partials, float* __restrict__ present)
{
    __shared__ Frag  abuf[2][256];         // 2 x 4KB A-fragment buffers
    __shared__ float comp[RPB][66];        // C tile, +2 pad (bank-spread)
    __shared__ float pmax[4][REDUC];

    const int t   = threadIdx.x;
    const int l   = t & 63;
    const int w   = t >> 6;
    const int blk = blockIdx.x;
    const int b   = blockIdx.y;

    // staging geometry: thread t stages slot t = (s2*2 + mt)*64 + l
    const int s2s  = t >> 7;               // K-substep staged
    const int mts  = (t >> 6) & 1;         // M-tile staged
    const int rloc = 16 * mts + (l & 15);  // row staged
    {
        int rr = blk * RPB + rloc;
        int rc = (rr < N_ROWS) ? rr : 0;   // clamp pad rows (discarded later)
        int tt = (rc < N_SAMP) ? rc * SR : (T_FULL - N_LOC) + (rc - N_SAMP);
        const float* xptr = obs + ((size_t)b * T_FULL + tt) * DIM
                            + 32 * s2s + 8 * (l >> 4);

        const int mt = w >> 1, nh = w & 1;
        f32x4 acc0 = {0.f, 0.f, 0.f, 0.f};
        f32x4 acc1 = {0.f, 0.f, 0.f, 0.f};

        // prologue: stage chunk 0 -> buf 0
        {
            float4 xa = *(const float4*)(xptr);
            float4 xb = *(const float4*)(xptr + 4);
            Frag fr;
            fr.u.x = pack2(xa.x, xa.y); fr.u.y = pack2(xa.z, xa.w);
            fr.u.z = pack2(xb.x, xb.y); fr.u.w = pack2(xb.z, xb.w);
            abuf[0][t] = fr;
        }
        __syncthreads();

        for (int c = 0; c < 8; ++c) {
            if (c < 7) {                   // prefetch chunk c+1 -> other buf
                float4 xa = *(const float4*)(xptr + 64 * (c + 1));
                float4 xb = *(const float4*)(xptr + 64 * (c + 1) + 4);
                Frag fr;
                fr.u.x = pack2(xa.x, xa.y); fr.u.y = pack2(xa.z, xa.w);
                fr.u.z = pack2(xb.x, xb.y); fr.u.w = pack2(xb.z, xb.w);
                abuf[(c & 1) ^ 1][t] = fr;
            }
#pragma unroll
            for (int s2 = 0; s2 < 2; ++s2) {
                Frag A = abuf[c & 1][(s2 * 2 + mt) * 64 + l];
                const int sg = c * 2 + s2;
                Frag B0, B1;
                B0.u = w1p[(sg * 4 + 2 * nh + 0) * 64 + l];
                B1.u = w1p[(sg * 4 + 2 * nh + 1) * 64 + l];
                acc0 = __builtin_amdgcn_mfma_f32_16x16x32_bf16(A.v, B0.v, acc0, 0, 0, 0);
                acc1 = __builtin_amdgcn_mfma_f32_16x16x32_bf16(A.v, B1.v, acc1, 0, 0, 0);
            }
            __syncthreads();
        }

        // write C: D[m=(l>>4)*4+reg][n=l&15] per tile
        const int crow = 16 * mt + 4 * (l >> 4);
        const int ccol = 32 * nh + (l & 15);
#pragma unroll
        for (int r = 0; r < 4; ++r) {
            comp[crow + r][ccol]      = acc0[r];
            comp[crow + r][ccol + 16] = acc1[r];
        }
    }
    __syncthreads();

    // LN epilogue: wave w owns rows 8w..8w+7; lane l = output dim j
    const float g1v = g1[l], be1v = beta1[l], b1v = b1[l];
    float wmax = -INFINITY;
#pragma unroll
    for (int r8 = 0; r8 < 8; ++r8) {
        int rl  = w * 8 + r8;
        int rr2 = blk * RPB + rl;
        float y = fmaxf(comp[rl][l] + b1v, 0.f);
        float s = y;
#pragma unroll
        for (int off = 32; off >= 1; off >>= 1) s += __shfl_xor(s, off);
        float mu = s * (1.f / 64.f);
        float d  = y - mu;
        float v  = d * d;
#pragma unroll
        for (int off = 32; off >= 1; off >>= 1) v += __shfl_xor(v, off);
        float cres = d * rsqrtf(v * (1.f / 64.f) + EPS) * g1v + be1v;

        if (rr2 < N_SAMP) {
            wmax = fmaxf(wmax, cres);
        } else if (rr2 < N_ROWS) {
            present[((size_t)b * N_LOC + (rr2 - N_SAMP)) * REDUC + l] = cres;
        }
    }

    pmax[w][l] = wmax;
    __syncthreads();
    if (w == 0 && blk < NPART) {
        float m = fmaxf(fmaxf(pmax[0][l], pmax[1][l]),
                        fmaxf(pmax[2][l], pmax[3][l]));
        partials[((size_t)b * NPART + blk) * REDUC + l] = m;
    }
}

// k2: per (batch, local-step): g = max(partials, cummax(present[0..t]));
// out = LN(relu(g @ W2 + b2)). 512 threads; max phase parallel over 8 slices.
__global__ __launch_bounds__(512) void k2_out(
        const float* __restrict__ partials,
        const float* __restrict__ present,
        const float* __restrict__ W2, const float* __restrict__ b2,
        const float* __restrict__ g2, const float* __restrict__ beta2,
        float* __restrict__ out)
{
    __shared__ float msh[8][REDUC];
    __shared__ float gsh[REDUC];
    __shared__ float red[16];

    const int b   = blockIdx.x / N_LOC;
    const int t   = blockIdx.x % N_LOC;
    const int tid = threadIdx.x;
    const int j   = tid & 63;
    const int s8  = tid >> 6;

    float m = -INFINITY;
    for (int p = s8; p < NPART; p += 8)
        m = fmaxf(m, partials[((size_t)b * NPART + p) * REDUC + j]);
    for (int r = s8; r <= t; r += 8)
        m = fmaxf(m, present[((size_t)b * N_LOC + r) * REDUC + j]);
    msh[s8][j] = m;
    __syncthreads();
    if (tid < REDUC) {
        float mm = msh[0][tid];
#pragma unroll
        for (int ss = 1; ss < 8; ++ss) mm = fmaxf(mm, msh[ss][tid]);
        gsh[tid] = mm;
    }
    __syncthreads();

    float acc = b2[tid];
#pragma unroll 8
    for (int k = 0; k < REDUC; ++k)
        acc = fmaf(gsh[k], W2[k * DIM + tid], acc);
    float y = fmaxf(acc, 0.f);

    const int lane = tid & 63, wv = tid >> 6;
    float s = y;
#pragma unroll
    for (int off = 32; off >= 1; off >>= 1) s += __shfl_xor(s, off);
    if (lane == 0) red[wv] = s;
    __syncthreads();
    float tot = red[0] + red[1] + red[2] + red[3] +
                red[4] + red[5] + red[6] + red[7];
    float mu = tot * (1.f / 512.f);
    float d  = y - mu;

    float v = d * d;
#pragma unroll
    for (int off = 32; off >= 1; off >>= 1) v += __shfl_xor(v, off);
    if (lane == 0) red[8 + wv] = v;
    __syncthreads();
    float vtot = red[8] + red[9] + red[10] + red[11] +
                 red[12] + red[13] + red[14] + red[15];
    float var = vtot * (1.f / 512.f);

    out[((size_t)b * N_LOC + t) * DIM + tid] =
        d * rsqrtf(var + EPS) * g2[tid] + beta2[tid];
}

extern "C" void kernel_launch(void* const* d_in, const int* in_sizes, int n_in,
                              void* d_out, int out_size, void* d_ws, size_t ws_size,
                              hipStream_t stream) {
    const float* obs   = (const float*)d_in[0];
    const float* W1    = (const float*)d_in[1];
    const float* b1    = (const float*)d_in[2];
    const float* g1    = (const float*)d_in[3];
    const float* beta1 = (const float*)d_in[4];
    const float* W2    = (const float*)d_in[5];
    const float* b2    = (const float*)d_in[6];
    const float* g2    = (const float*)d_in[7];
    const float* beta2 = (const float*)d_in[8];
    float* out = (float*)d_out;

    // ws: w1p (64KB) | partials [32][13][64] f32 | present [32][20][64] f32
    uint4* w1p      = (uint4*)d_ws;
    float* partials = (float*)((char*)d_ws + 65536);
    float* present  = partials + (size_t)NB * NPART * REDUC;

    k0_pack<<<16, 256, 0, stream>>>(W1, w1p);
    dim3 g1d(BPB, NB);
    k1_rows<<<g1d, 256, 0, stream>>>(obs, w1p, b1, g1, beta1, partials, present);
    k2_out<<<NB * N_LOC, 512, 0, stream>>>(partials, present, W2, b2, g2, beta2, out);
}

// Round 5
// 27.645 us; speedup vs baseline: 3.9913x; 1.0356x over previous
//
#include <hip/hip_runtime.h>
#include <math.h>

#define DIM    512
#define REDUC  64
#define T_FULL 4096
#define NB     32
#define SR     10
#define N_SAMP 408     // t = 0,10,...,4070
#define N_LOC  20
#define N_ROWS 428     // per batch: 408 sampled + 20 local
#define EPS    1e-5f

#define RPB   32       // rows per block (2 M-tiles of 16)
#define BPB   14       // blocks per batch (block 13: 12 local-only rows)
#define NPART 13       // blocks containing sampled rows

typedef short bf16x8 __attribute__((ext_vector_type(8)));   // 8 bf16 in 4 VGPRs
typedef float f32x4  __attribute__((ext_vector_type(4)));

union Frag { bf16x8 v; uint4 u; };

__device__ __forceinline__ unsigned bf16_rne(float f) {     // round-nearest-even
    unsigned u = __float_as_uint(f);
    return (u + 0x7fffu + ((u >> 16) & 1u)) >> 16;
}
__device__ __forceinline__ unsigned pack2(float lo, float hi) {
    return bf16_rne(lo) | (bf16_rne(hi) << 16);
}

// k0: pre-pack W1 (f32 [512][64]) into bf16 B-fragment order:
// w1p[sg][tile][lane] (16B): lane l holds W1[32*sg + 8*(l>>4) + f][16*tile + (l&15)]
__global__ __launch_bounds__(256) void k0_pack(const float* __restrict__ W1,
                                               uint4* __restrict__ w1p) {
    const int sg = blockIdx.x;                 // K-step 0..15
    const int t  = threadIdx.x;
    const int tile = t >> 6, l = t & 63;
    const int k0 = 32 * sg + 8 * (l >> 4);
    const int j  = 16 * tile + (l & 15);
    float v[8];
#pragma unroll
    for (int f = 0; f < 8; ++f) v[f] = W1[(size_t)(k0 + f) * REDUC + j];
    uint4 o;
    o.x = pack2(v[0], v[1]); o.y = pack2(v[2], v[3]);
    o.z = pack2(v[4], v[5]); o.w = pack2(v[6], v[7]);
    w1p[sg * 256 + t] = o;
}

// k1: comp = LN(relu(x @ W1 + b1)) for the 428 needed rows per batch via
// bf16 MFMA 16x16x32. Block = 4 waves = 32 rows x 64 j. Wave w: M-tile w>>1,
// N-half w&1. Single-shot staging: all 16 dwordx4 loads issued up front
// (one HBM latency), f32->bf16 pack, one barrier, then pure MFMA loop.
__global__ __launch_bounds__(256) void k1_rows(
        const float* __restrict__ obs, const uint4* __restrict__ w1p,
        const float* __restrict__ b1, const float* __restrict__ g1,
        const float* __restrict__ beta1,
        float* __restrict__ partials, float* __restrict__ present)
{
    __shared__ Frag  abuf[8][256];         // 32 KB: whole 32x512 x-tile as bf16
    __shared__ float comp[RPB][66];        // C tile, +2 pad
    __shared__ float pmax[4][REDUC];

    const int t   = threadIdx.x;
    const int l   = t & 63;
    const int w   = t >> 6;
    const int blk = blockIdx.x;
    const int b   = blockIdx.y;

    // staging geometry: thread t stages slot t of each chunk:
    // row 16*mts + (l&15), k-offset 32*s2s + 8*(l>>4) (+64 per chunk)
    const int s2s  = t >> 7;
    const int mts  = (t >> 6) & 1;
    const int rloc = 16 * mts + (l & 15);
    int rr = blk * RPB + rloc;
    int rc = (rr < N_ROWS) ? rr : 0;       // clamp pad rows (discarded later)
    int tt = (rc < N_SAMP) ? rc * SR : (T_FULL - N_LOC) + (rc - N_SAMP);
    const float* xptr = obs + ((size_t)b * T_FULL + tt) * DIM
                        + 32 * s2s + 8 * (l >> 4);

    // issue ALL x loads (16 dwordx4/thread in flight), then pack -> LDS
    float4 xa[8], xb[8];
#pragma unroll
    for (int c = 0; c < 8; ++c) {
        xa[c] = *(const float4*)(xptr + 64 * c);
        xb[c] = *(const float4*)(xptr + 64 * c + 4);
    }
#pragma unroll
    for (int c = 0; c < 8; ++c) {
        Frag fr;
        fr.u.x = pack2(xa[c].x, xa[c].y); fr.u.y = pack2(xa[c].z, xa[c].w);
        fr.u.z = pack2(xb[c].x, xb[c].y); fr.u.w = pack2(xb[c].z, xb[c].w);
        abuf[c][t] = fr;
    }
    __syncthreads();

    const int mt = w >> 1, nh = w & 1;
    f32x4 acc0 = {0.f, 0.f, 0.f, 0.f};
    f32x4 acc1 = {0.f, 0.f, 0.f, 0.f};
#pragma unroll
    for (int c = 0; c < 8; ++c) {
#pragma unroll
        for (int s2 = 0; s2 < 2; ++s2) {
            Frag A; A.u = abuf[c][(s2 * 2 + mt) * 64 + l].u;
            const int sg = c * 2 + s2;
            Frag B0, B1;
            B0.u = w1p[(sg * 4 + 2 * nh + 0) * 64 + l];
            B1.u = w1p[(sg * 4 + 2 * nh + 1) * 64 + l];
            acc0 = __builtin_amdgcn_mfma_f32_16x16x32_bf16(A.v, B0.v, acc0, 0, 0, 0);
            acc1 = __builtin_amdgcn_mfma_f32_16x16x32_bf16(A.v, B1.v, acc1, 0, 0, 0);
        }
    }

    // write C: D[m=(l>>4)*4+reg][n=l&15] per 16x16 tile
    const int crow = 16 * mt + 4 * (l >> 4);
    const int ccol = 32 * nh + (l & 15);
#pragma unroll
    for (int r = 0; r < 4; ++r) {
        comp[crow + r][ccol]      = acc0[r];
        comp[crow + r][ccol + 16] = acc1[r];
    }
    __syncthreads();

    // LN epilogue: wave w owns rows 8w..8w+7; lane l = output dim j
    const float g1v = g1[l], be1v = beta1[l], b1v = b1[l];
    float wmax = -INFINITY;
#pragma unroll
    for (int r8 = 0; r8 < 8; ++r8) {
        int rl  = w * 8 + r8;
        int rr2 = blk * RPB + rl;
        float y = fmaxf(comp[rl][l] + b1v, 0.f);
        float s = y;
#pragma unroll
        for (int off = 32; off >= 1; off >>= 1) s += __shfl_xor(s, off);
        float mu = s * (1.f / 64.f);
        float d  = y - mu;
        float v  = d * d;
#pragma unroll
        for (int off = 32; off >= 1; off >>= 1) v += __shfl_xor(v, off);
        float cres = d * rsqrtf(v * (1.f / 64.f) + EPS) * g1v + be1v;

        if (rr2 < N_SAMP) {
            wmax = fmaxf(wmax, cres);
        } else if (rr2 < N_ROWS) {
            present[((size_t)b * N_LOC + (rr2 - N_SAMP)) * REDUC + l] = cres;
        }
    }

    pmax[w][l] = wmax;
    __syncthreads();
    if (w == 0 && blk < NPART) {
        float m = fmaxf(fmaxf(pmax[0][l], pmax[1][l]),
                        fmaxf(pmax[2][l], pmax[3][l]));
        partials[((size_t)b * NPART + blk) * REDUC + l] = m;
    }
}

// k2: per (batch, local-step): g = max(partials, cummax(present[0..t]));
// out = LN(relu(g @ W2 + b2)). 512 threads; max phase parallel over 8 slices.
__global__ __launch_bounds__(512) void k2_out(
        const float* __restrict__ partials,
        const float* __restrict__ present,
        const float* __restrict__ W2, const float* __restrict__ b2,
        const float* __restrict__ g2, const float* __restrict__ beta2,
        float* __restrict__ out)
{
    __shared__ float msh[8][REDUC];
    __shared__ float gsh[REDUC];
    __shared__ float red[16];

    const int b   = blockIdx.x / N_LOC;
    const int t   = blockIdx.x % N_LOC;
    const int tid = threadIdx.x;
    const int j   = tid & 63;
    const int s8  = tid >> 6;

    float m = -INFINITY;
    for (int p = s8; p < NPART; p += 8)
        m = fmaxf(m, partials[((size_t)b * NPART + p) * REDUC + j]);
    for (int r = s8; r <= t; r += 8)
        m = fmaxf(m, present[((size_t)b * N_LOC + r) * REDUC + j]);
    msh[s8][j] = m;
    __syncthreads();
    if (tid < REDUC) {
        float mm = msh[0][tid];
#pragma unroll
        for (int ss = 1; ss < 8; ++ss) mm = fmaxf(mm, msh[ss][tid]);
        gsh[tid] = mm;
    }
    __syncthreads();

    float acc = b2[tid];
#pragma unroll 8
    for (int k = 0; k < REDUC; ++k)
        acc = fmaf(gsh[k], W2[k * DIM + tid], acc);
    float y = fmaxf(acc, 0.f);

    const int lane = tid & 63, wv = tid >> 6;
    float s = y;
#pragma unroll
    for (int off = 32; off >= 1; off >>= 1) s += __shfl_xor(s, off);
    if (lane == 0) red[wv] = s;
    __syncthreads();
    float tot = red[0] + red[1] + red[2] + red[3] +
                red[4] + red[5] + red[6] + red[7];
    float mu = tot * (1.f / 512.f);
    float d  = y - mu;

    float v = d * d;
#pragma unroll
    for (int off = 32; off >= 1; off >>= 1) v += __shfl_xor(v, off);
    if (lane == 0) red[8 + wv] = v;
    __syncthreads();
    float vtot = red[8] + red[9] + red[10] + red[11] +
                 red[12] + red[13] + red[14] + red[15];
    float var = vtot * (1.f / 512.f);

    out[((size_t)b * N_LOC + t) * DIM + tid] =
        d * rsqrtf(var + EPS) * g2[tid] + beta2[tid];
}

extern "C" void kernel_launch(void* const* d_in, const int* in_sizes, int n_in,
                              void* d_out, int out_size, void* d_ws, size_t ws_size,
                              hipStream_t stream) {
    const float* obs   = (const float*)d_in[0];
    const float* W1    = (const float*)d_in[1];
    const float* b1    = (const float*)d_in[2];
    const float* g1    = (const float*)d_in[3];
    const float* beta1 = (const float*)d_in[4];
    const float* W2    = (const float*)d_in[5];
    const float* b2    = (const float*)d_in[6];
    const float* g2    = (const float*)d_in[7];
    const float* beta2 = (const float*)d_in[8];
    float* out = (float*)d_out;

    // ws: w1p (64KB) | partials [32][13][64] f32 | present [32][20][64] f32
    uint4* w1p      = (uint4*)d_ws;
    float* partials = (float*)((char*)d_ws + 65536);
    float* present  = partials + (size_t)NB * NPART * REDUC;

    k0_pack<<<16, 256, 0, stream>>>(W1, w1p);
    dim3 g1d(BPB, NB);
    k1_rows<<<g1d, 256, 0, stream>>>(obs, w1p, b1, g1, beta1, partials, present);
    k2_out<<<NB * N_LOC, 512, 0, stream>>>(partials, present, W2, b2, g2, beta2, out);
}